// Round 4
// baseline (208.601 us; speedup 1.0000x reference)
//
#include <hip/hip_runtime.h>
#include <hip/hip_bf16.h>
#include <float.h>

// Problem constants: N=32768 rows, C=1000 classes.
#define RL_N 32768
#define RL_C 1000
#define NVEC 250              // RL_C/4 float4s per row
#define TILE 32

#define ROW_BLOCKS 2048
#define WPB 4                 // waves per block (256 threads)
#define TOTAL_WAVES (ROW_BLOCKS * WPB)   // 8192
#define RPW (RL_N / TOTAL_WAVES)         // 4 rows per wave

typedef float v4f __attribute__((ext_vector_type(4)));

__device__ __forceinline__ v4f ntload4(const float* p) {
  return __builtin_nontemporal_load((const v4f*)p);   // global_load_dwordx4 ... nt
}
__device__ __forceinline__ v4f ld4(const float* p) { return *(const v4f*)p; }

// ------------- K1: Tiled transpose Tt[y][j] = T[j][y]; block 0 zeroes bins -------------
__global__ __launch_bounds__(256) void transpose_kernel(
    const float* __restrict__ in, float* __restrict__ outp,
    int* __restrict__ bins, int n) {
  if (blockIdx.x == 0 && blockIdx.y == 0) {
    for (int i = threadIdx.y * TILE + threadIdx.x; i < RL_C; i += 256) bins[i] = 0;
  }
  __shared__ float tile[TILE][TILE + 1];
  int x = blockIdx.x * TILE + threadIdx.x;
  int y = blockIdx.y * TILE + threadIdx.y;
#pragma unroll
  for (int k = 0; k < TILE; k += 8) {
    int yy = y + k;
    if (x < n && yy < n) tile[threadIdx.y + k][threadIdx.x] = in[(size_t)yy * n + x];
  }
  __syncthreads();
  x = blockIdx.y * TILE + threadIdx.x;
  y = blockIdx.x * TILE + threadIdx.y;
#pragma unroll
  for (int k = 0; k < TILE; k += 8) {
    int yy = y + k;
    if (x < n && yy < n) outp[(size_t)yy * n + x] = tile[threadIdx.x][threadIdx.y + k];
  }
}

// ------------- K2: histogram of target into bins (LDS-privatized) -------------
#define HIST_BLOCKS 64
#define HIST_THREADS 512
__global__ __launch_bounds__(HIST_THREADS) void hist_kernel(
    const int* __restrict__ target, int* __restrict__ bins) {
  __shared__ int h[RL_C];
  for (int i = threadIdx.x; i < RL_C; i += HIST_THREADS) h[i] = 0;
  __syncthreads();
  const int i = blockIdx.x * HIST_THREADS + threadIdx.x;   // 64*512 = 32768 exact
  atomicAdd(&h[target[i]], 1);
  __syncthreads();
  for (int i2 = threadIdx.x; i2 < RL_C; i2 += HIST_THREADS)
    if (h[i2]) atomicAdd(&bins[i2], h[i2]);
}

// ------------- K3: exclusive scan of bins -> offsets (1 block) -------------
__global__ __launch_bounds__(1024) void scan_kernel(
    const int* __restrict__ bins, int* __restrict__ offsets) {
  __shared__ int s[1024];
  const int tid = threadIdx.x;
  const int own = (tid < RL_C) ? bins[tid] : 0;
  s[tid] = own;
#pragma unroll
  for (int off = 1; off < 1024; off <<= 1) {
    __syncthreads();
    int v = (tid >= off) ? s[tid - off] : 0;
    __syncthreads();
    s[tid] += v;
  }
  __syncthreads();
  if (tid < RL_C) offsets[tid] = s[tid] - own;   // exclusive
}

// ------------- K4: scatter row ids into perm (y-sorted order) -------------
__global__ __launch_bounds__(256) void scatter_kernel(
    const int* __restrict__ target, int* __restrict__ offsets,
    int* __restrict__ perm) {
  const int i = blockIdx.x * 256 + threadIdx.x;   // 128*256 = 32768 exact
  const int y = target[i];
  const int pos = atomicAdd(&offsets[y], 1);
  perm[pos] = i;
}

// ---------------- Wave (64-lane) sum reduction, result on lane 0 ----------------
__device__ __forceinline__ float wredsum_l0(float v) {
#pragma unroll
  for (int o = 32; o > 0; o >>= 1) v += __shfl_down(v, o, 64);
  return v;
}

// ------------- K5: row kernel — one WAVE per row, 4 y-sorted rows per wave -------------
// No max-subtraction (logits ~ N(0,1): exp safe in fp32; shift cancels in beta & ce).
__global__ __launch_bounds__(256) void row_kernel(
    const float* __restrict__ logits, const float* __restrict__ Tt,
    const int* __restrict__ target, const int* __restrict__ perm,
    float* __restrict__ partial) {
  const int tid  = threadIdx.x;
  const int lane = tid & 63;
  const int wid  = tid >> 6;
  const int wave = blockIdx.x * WPB + wid;
  const int row0 = wave * RPW;

  const bool tail = lane < (NVEC - 192);   // lane < 58 holds a 4th vec

  // y-sorted row ids + labels (wave-uniform scalar loads)
  int rows[RPW], ys[RPW];
#pragma unroll
  for (int r = 0; r < RPW; ++r) {
    rows[r] = perm[row0 + r];
    ys[r]   = target[rows[r]];
  }

  const v4f NEGBIG = {-FLT_MAX, -FLT_MAX, -FLT_MAX, -FLT_MAX};
  const v4f ZERO4  = {0.f, 0.f, 0.f, 0.f};

  v4f ov[2][4], tv[2][4];

  {
    const float* o = logits + (size_t)rows[0] * RL_C;
    const float* t = Tt + (size_t)ys[0] * RL_C;
    ov[0][0] = ntload4(o + 4 * lane);
    ov[0][1] = ntload4(o + 4 * (lane + 64));
    ov[0][2] = ntload4(o + 4 * (lane + 128));
    ov[0][3] = tail ? ntload4(o + 4 * (lane + 192)) : NEGBIG;
    tv[0][0] = ld4(t + 4 * lane);
    tv[0][1] = ld4(t + 4 * (lane + 64));
    tv[0][2] = ld4(t + 4 * (lane + 128));
    tv[0][3] = tail ? ld4(t + 4 * (lane + 192)) : ZERO4;
  }

  float s1[RPW], s2[RPW], oy[RPW];

#pragma unroll
  for (int r = 0; r < RPW; ++r) {
    const int cur = r & 1, nxt = cur ^ 1;

    if (r + 1 < RPW) {
      const float* o = logits + (size_t)rows[r + 1] * RL_C;
      const float* t = Tt + (size_t)ys[r + 1] * RL_C;   // usually same y -> L1-hit
      ov[nxt][0] = ntload4(o + 4 * lane);
      ov[nxt][1] = ntload4(o + 4 * (lane + 64));
      ov[nxt][2] = ntload4(o + 4 * (lane + 128));
      ov[nxt][3] = tail ? ntload4(o + 4 * (lane + 192)) : NEGBIG;
      tv[nxt][0] = ld4(t + 4 * lane);
      tv[nxt][1] = ld4(t + 4 * (lane + 64));
      tv[nxt][2] = ld4(t + 4 * (lane + 128));
      tv[nxt][3] = tail ? ld4(t + 4 * (lane + 192)) : ZERO4;
    }

    float a1 = 0.f, a2 = 0.f;
#pragma unroll
    for (int k = 0; k < 4; ++k) {
      float ex = __expf(ov[cur][k].x);
      float ey = __expf(ov[cur][k].y);
      float ez = __expf(ov[cur][k].z);
      float ew = __expf(ov[cur][k].w);
      a1 += (ex + ey) + (ez + ew);
      a2 += (ex * tv[cur][k].x + ey * tv[cur][k].y)
          + (ez * tv[cur][k].z + ew * tv[cur][k].w);
    }
    s1[r] = a1;
    s2[r] = a2;

    // extract o_y from registers (wave-uniform selectors)
    const int v = ys[r] >> 2;
    const int c = v >> 6;
    const int owner = v & 63;
    const int comp = ys[r] & 3;
    v4f f = (c == 0) ? ov[cur][0] : (c == 1) ? ov[cur][1]
          : (c == 2) ? ov[cur][2] : ov[cur][3];
    float sel = (comp == 0) ? f.x : (comp == 1) ? f.y : (comp == 2) ? f.z : f.w;
    oy[r] = __shfl(sel, owner, 64);
  }

  // deferred reductions: 8 independent shuffle chains
  float s1t[RPW], s2t[RPW];
#pragma unroll
  for (int r = 0; r < RPW; ++r) {
    s1t[r] = wredsum_l0(s1[r]);
    s2t[r] = wredsum_l0(s2[r]);
  }

  float acc = 0.f;
  if (lane == 0) {
#pragma unroll
    for (int r = 0; r < RPW; ++r) {
      const float beta = __expf(oy[r]) / s2t[r];
      const float ce   = __logf(s1t[r]) - oy[r];
      acc += beta * ce;
    }
  }

  __shared__ float sm[WPB];
  if (lane == 0) sm[wid] = acc;
  __syncthreads();
  if (tid == 0) partial[blockIdx.x] = (sm[0] + sm[1]) + (sm[2] + sm[3]);
}

// ------------- K6: final reduction over ROW_BLOCKS partials -------------
__global__ __launch_bounds__(256) void reduce_kernel(
    const float* __restrict__ partial, float* __restrict__ outp, float inv_n) {
  const int tid  = threadIdx.x;
  const int lane = tid & 63;
  const int wid  = tid >> 6;
  float s = 0.f;
#pragma unroll
  for (int i = tid; i < ROW_BLOCKS; i += 256) s += partial[i];
  float ws = wredsum_l0(s);
  __shared__ float sm[4];
  if (lane == 0) sm[wid] = ws;
  __syncthreads();
  if (tid == 0) outp[0] = ((sm[0] + sm[1]) + (sm[2] + sm[3])) * inv_n;
}

extern "C" void kernel_launch(void* const* d_in, const int* in_sizes, int n_in,
                              void* d_out, int out_size, void* d_ws, size_t ws_size,
                              hipStream_t stream) {
  const float* logits = (const float*)d_in[0];   // [N, C] fp32
  const float* T      = (const float*)d_in[1];   // [C, C] fp32
  const int*   target = (const int*)d_in[2];     // [N] int32
  float* outp = (float*)d_out;

  // Workspace layout (16B-aligned segments):
  //   Tt:      4,000,000 B @ 0
  //   partial:     8,192 B @ 4,000,000
  //   bins:        4,000 B @ 4,008,192
  //   offsets:     4,000 B @ 4,012,192
  //   perm:      131,072 B @ 4,016,192
  char* ws = (char*)d_ws;
  float* Tt      = (float*)(ws);
  float* partial = (float*)(ws + 4000000);
  int*   bins    = (int*)(ws + 4008192);
  int*   offsets = (int*)(ws + 4012192);
  int*   perm    = (int*)(ws + 4016192);

  dim3 tb(TILE, 8);
  dim3 tg((RL_C + TILE - 1) / TILE, (RL_C + TILE - 1) / TILE);
  transpose_kernel<<<tg, tb, 0, stream>>>(T, Tt, bins, RL_C);

  hist_kernel<<<HIST_BLOCKS, HIST_THREADS, 0, stream>>>(target, bins);
  scan_kernel<<<1, 1024, 0, stream>>>(bins, offsets);
  scatter_kernel<<<RL_N / 256, 256, 0, stream>>>(target, offsets, perm);

  row_kernel<<<ROW_BLOCKS, 256, 0, stream>>>(logits, Tt, target, perm, partial);

  reduce_kernel<<<1, 256, 0, stream>>>(partial, outp, 1.0f / (float)RL_N);
}